// Round 5
// baseline (570.246 us; speedup 1.0000x reference)
//
#include <hip/hip_runtime.h>
#include <math.h>
#include <float.h>

#define K_CODES 8192
#define C_DIM   256
#define N_TOK   16384
#define B_      16
#define H_      32
#define W_      32
#define HW      1024
#define KSPLIT  8

typedef short  short8   __attribute__((ext_vector_type(8)));
typedef float  floatx16 __attribute__((ext_vector_type(16)));

__device__ inline ushort f32_to_bf16_rne(float x) {
    union { float f; unsigned u; } v; v.f = x;
    unsigned u = v.u;
    return (ushort)((u + 0x7FFFu + ((u >> 16) & 1u)) >> 16);
}
__device__ inline float bf16_bits_to_f32(ushort h) {
    union { unsigned u; float f; } v; v.u = ((unsigned)h) << 16;
    return v.f;
}
__device__ inline unsigned umax_(unsigned a, unsigned b) { return a > b ? a : b; }
__device__ inline unsigned umin_(unsigned a, unsigned b) { return a < b ? a : b; }

__device__ inline void g2l16(const void* g, void* l) {
    __builtin_amdgcn_global_load_lds((const __attribute__((address_space(1))) unsigned int*)g,
                                     (__attribute__((address_space(3))) unsigned int*)l,
                                     16, 0, 0);
}

// Swizzled bf16 layout for 32x32x16 MFMA frags (rows x 256 ch):
//   byte addr = RG*16384 + p*16, p = CB*64 + h*32 + r
//   (RG = row>>5, CB = ch>>4, h = (ch>>3)&1, r = row&31)
// A frag (32 rows x 16 ch) = contiguous 1KB at RG*16384 + CB*1024; lane l
// (r = l&31, h = l>>5) reads +l*16 -> row r, ch CB*16 + h*8 .. +8. Same for B.

// ---------------------------------------------------------------------------
// Kernel 1 (fused): bid<256 -> codebook (32 codes): e_n fp32, s2, swizzled
// Chi/Clo. bid>=256 -> tokens ((b,h), 32 tokens): ztn fp32, swizzled Thi/Tlo.
// ---------------------------------------------------------------------------
__global__ __launch_bounds__(256) void norm_pack(
        const float* __restrict__ emb, const float* __restrict__ z,
        float* __restrict__ e_n, float* __restrict__ s2,
        ushort* __restrict__ Chi, ushort* __restrict__ Clo,
        float* __restrict__ ztn, ushort* __restrict__ Thi, ushort* __restrict__ Tlo) {
    __shared__ float tile[32][257];
    __shared__ float pvt[32][9];
    __shared__ float pvt2[32][9];
    __shared__ float inv[32];
    int t = threadIdx.x;
    int bid = blockIdx.x;
    if (bid < 256) {
        // ---- codebook path ----
        int k0 = bid * 32;
        int r = t >> 3, cp = t & 7;
        const float* src = emb + (size_t)(k0 + r) * C_DIM + cp * 32;
        float ss = 0.f;
        #pragma unroll
        for (int j = 0; j < 8; ++j) {
            float4 v = *(const float4*)(src + j * 4);
            tile[r][cp * 32 + j * 4 + 0] = v.x;
            tile[r][cp * 32 + j * 4 + 1] = v.y;
            tile[r][cp * 32 + j * 4 + 2] = v.z;
            tile[r][cp * 32 + j * 4 + 3] = v.w;
            ss = fmaf(v.x, v.x, ss); ss = fmaf(v.y, v.y, ss);
            ss = fmaf(v.z, v.z, ss); ss = fmaf(v.w, v.w, ss);
        }
        pvt[r][cp] = ss;
        __syncthreads();
        if (t < 32) {
            float a = 0.f;
            #pragma unroll
            for (int p = 0; p < 8; ++p) a += pvt[t][p];
            inv[t] = 1.0f / fmaxf(sqrtf(a), 1e-12f);
        }
        __syncthreads();
        float iv = inv[r];
        float s2p = 0.f;
        float* dst = e_n + (size_t)(k0 + r) * C_DIM + cp * 32;
        #pragma unroll
        for (int j = 0; j < 8; ++j) {
            float a = tile[r][cp * 32 + j * 4 + 0] * iv;
            float b = tile[r][cp * 32 + j * 4 + 1] * iv;
            float c = tile[r][cp * 32 + j * 4 + 2] * iv;
            float d = tile[r][cp * 32 + j * 4 + 3] * iv;
            s2p = fmaf(a, a, s2p); s2p = fmaf(b, b, s2p);
            s2p = fmaf(c, c, s2p); s2p = fmaf(d, d, s2p);
            float4 o = {a, b, c, d};
            *(float4*)(dst + j * 4) = o;
        }
        pvt2[r][cp] = s2p;
        __syncthreads();
        if (t < 32) {
            float a = 0.f;
            #pragma unroll
            for (int p = 0; p < 8; ++p) a += pvt2[t][p];
            s2[k0 + t] = a;
        }
        // swizzled pack (RG = bid)
        char* chiB = (char*)Chi;
        char* cloB = (char*)Clo;
        #pragma unroll
        for (int e = 0; e < 4; ++e) {
            int p = e * 256 + t;
            int row = p & 31;
            int ch0 = ((p >> 6) << 4) | (((p >> 5) & 1) << 3);
            float rv = inv[row];
            union { ushort u[8]; uint4 v; } hs, ls;
            #pragma unroll
            for (int i = 0; i < 8; ++i) {
                float vv = tile[row][ch0 + i] * rv;
                ushort hb = f32_to_bf16_rne(vv);
                hs.u[i] = hb;
                ls.u[i] = f32_to_bf16_rne(vv - bf16_bits_to_f32(hb));
            }
            size_t addr = (size_t)bid * 16384 + (size_t)p * 16;
            *(uint4*)(chiB + addr) = hs.v;
            *(uint4*)(cloB + addr) = ls.v;
        }
    } else {
        // ---- token path ----
        int tb = bid - 256;            // b*32 + h, RG = tb
        int b = tb >> 5, h = tb & 31;
        int w = t & 31, c0 = t >> 5;
        const float* zb = z + ((size_t)(b * C_DIM) * H_ + h) * W_;
        #pragma unroll
        for (int it = 0; it < 32; ++it) {
            int c = it * 8 + c0;
            tile[w][c] = zb[(size_t)c * HW + w];
        }
        __syncthreads();
        int part = t >> 5, w2 = t & 31;
        float s = 0.f;
        #pragma unroll
        for (int i = 0; i < 32; ++i) {
            float v = tile[w2][part * 32 + i];
            s = fmaf(v, v, s);
        }
        pvt[w2][part] = s;
        __syncthreads();
        if (t < 32) {
            float ss = 0.f;
            #pragma unroll
            for (int p = 0; p < 8; ++p) ss += pvt[t][p];
            inv[t] = 1.0f / fmaxf(sqrtf(ss), 1e-12f);
        }
        __syncthreads();
        int n_base = tb * 32;
        for (int r = 0; r < 32; ++r) {
            float val = tile[r][t] * inv[r];
            ztn[(size_t)(n_base + r) * C_DIM + t] = val;
        }
        char* thiB = (char*)Thi;
        char* tloB = (char*)Tlo;
        #pragma unroll
        for (int e = 0; e < 4; ++e) {
            int p = e * 256 + t;
            int row = p & 31;
            int ch0 = ((p >> 6) << 4) | (((p >> 5) & 1) << 3);
            float rv = inv[row];
            union { ushort u[8]; uint4 v; } hs, ls;
            #pragma unroll
            for (int i = 0; i < 8; ++i) {
                float vv = tile[row][ch0 + i] * rv;
                ushort hb = f32_to_bf16_rne(vv);
                hs.u[i] = hb;
                ls.u[i] = f32_to_bf16_rne(vv - bf16_bits_to_f32(hb));
            }
            size_t addr = (size_t)tb * 16384 + (size_t)p * 16;
            *(uint4*)(thiB + addr) = hs.v;
            *(uint4*)(tloB + addr) = ls.v;
        }
    }
}

// ---------------------------------------------------------------------------
// Kernel 2: MFMA scan, 32x32x16 bf16. Block = 128 thr (2 waves), tile
// 64 tokens x 128 codes; wave = 64 tok x 64 codes (ct=2, nt=2, acc 64 VGPR).
// Codes via LDS (16KB, global_load_lds); token frags DIRECT global->VGPR
// (no LDS round-trip, wave-private). Grid (256, 8) = 2048 blocks = 8/CU.
// D[code][token]: col=lane&31 = token, row=(reg&3)+8*(reg>>2)+4*(lane>>5).
// Proper per-partition top-2 via packed keys (6 stolen mantissa bits).
// ---------------------------------------------------------------------------
__global__ __launch_bounds__(128, 4) void score_topk(
        const ushort* __restrict__ Chi, const ushort* __restrict__ Clo,
        const ushort* __restrict__ Thi, const ushort* __restrict__ Tlo,
        int* __restrict__ cand) {
    __shared__ __align__(16) char smem[16384];
    int t = threadIdx.x;
    int wv = t >> 6, l = t & 63;
    int h = l >> 5, col = l & 31;
    int tokBase = blockIdx.x * 64;
    int tokRG = tokBase >> 5;                 // 2 RGs per block
    int part = blockIdx.y;
    int partBase = part * (K_CODES / KSPLIT); // 1024 codes per partition

    unsigned rv1[2] = {0u, 0u}, rv2[2] = {0u, 0u};
    int ri1[2] = {0, 0}, ri2[2] = {0, 0};

    const char* chiB = (const char*)Chi;
    const char* cloB = (const char*)Clo;
    const char* thiB = (const char*)Thi;
    const char* tloB = (const char*)Tlo;

    for (int kt = 0; kt < (K_CODES / KSPLIT) / 128; ++kt) {   // 8 iters
        int kbase = partBase + kt * 128;
        int codeRG = kbase >> 5;              // 4 RGs per iter
        floatx16 acc[2][2];
        #pragma unroll
        for (int ct = 0; ct < 2; ++ct)
            #pragma unroll
            for (int nt = 0; nt < 2; ++nt)
                #pragma unroll
                for (int r = 0; r < 16; ++r) acc[ct][nt][r] = 0.f;

        for (int s = 0; s < 8; ++s) {
            __syncthreads();   // prior stage's readers done
            // stage 16KB of codes: 16 slices (hilo x 4RG x 2cb), 8 per wave
            #pragma unroll
            for (int gi = 0; gi < 8; ++gi) {
                int slice = wv * 8 + gi;
                int hilo = slice >> 3, rgl = (slice >> 1) & 3, cb = slice & 1;
                const char* gb = (hilo ? cloB : chiB)
                    + (size_t)(codeRG + rgl) * 16384 + s * 2048 + cb * 1024 + (l << 4);
                g2l16(gb, smem + (slice << 10));
            }
            // token frags: direct global->VGPR (issue before barrier drain)
            short8 bh[2][2], bl[2][2];        // [cb][nt]
            #pragma unroll
            for (int cb = 0; cb < 2; ++cb)
                #pragma unroll
                for (int nt = 0; nt < 2; ++nt) {
                    size_t ta = (size_t)(tokRG + nt) * 16384 + s * 2048 + cb * 1024 + (l << 4);
                    bh[cb][nt] = *(const short8*)(thiB + ta);
                    bl[cb][nt] = *(const short8*)(tloB + ta);
                }
            __syncthreads();   // DMA drained
            #pragma unroll
            for (int cb = 0; cb < 2; ++cb) {
                #pragma unroll
                for (int ct = 0; ct < 2; ++ct) {
                    int slice = (wv * 2 + ct) * 2 + cb;
                    short8 ah = *(const short8*)(smem + (slice << 10) + (l << 4));
                    short8 al = *(const short8*)(smem + ((8 + slice) << 10) + (l << 4));
                    #pragma unroll
                    for (int nt = 0; nt < 2; ++nt) {
                        acc[ct][nt] = __builtin_amdgcn_mfma_f32_32x32x16_bf16(al, bh[cb][nt], acc[ct][nt], 0, 0, 0);
                        acc[ct][nt] = __builtin_amdgcn_mfma_f32_32x32x16_bf16(ah, bl[cb][nt], acc[ct][nt], 0, 0, 0);
                        acc[ct][nt] = __builtin_amdgcn_mfma_f32_32x32x16_bf16(ah, bh[cb][nt], acc[ct][nt], 0, 0, 0);
                    }
                }
            }
        }
        // packed-key top-2 per token slot. key = bits(d*0.25+1.25) & ~63 | off,
        // off = ct<<5 | (reg&3)+8*(reg>>2)  (quantization ~3e-5 on d; exact
        // rescore later). d in [-1,1] -> value in [1.0,1.5), monotone u32.
        #pragma unroll
        for (int nt = 0; nt < 2; ++nt) {
            unsigned m1 = 0u, m2 = 0u;
            #pragma unroll
            for (int ct = 0; ct < 2; ++ct) {
                #pragma unroll
                for (int r = 0; r < 16; ++r) {
                    int off = (ct << 5) | ((r & 3) + 8 * (r >> 2));
                    unsigned key = (__float_as_uint(fmaf(acc[ct][nt][r], 0.25f, 1.25f)) & 0xFFFFFFC0u)
                                   | (unsigned)off;
                    m2 = umax_(m2, umin_(key, m1));
                    m1 = umax_(m1, key);
                }
            }
            int o1 = (int)(m1 & 63u), o2 = (int)(m2 & 63u);
            int c1 = kbase + ((wv * 2 + (o1 >> 5)) << 5) + (o1 & 31) + 4 * h;
            int c2 = kbase + ((wv * 2 + (o2 >> 5)) << 5) + (o2 & 31) + 4 * h;
            if (m1 > rv1[nt]) {
                if (m2 > rv1[nt]) { rv2[nt] = m2; ri2[nt] = c2; }
                else              { rv2[nt] = rv1[nt]; ri2[nt] = ri1[nt]; }
                rv1[nt] = m1; ri1[nt] = c1;
            } else if (m1 > rv2[nt]) {
                rv2[nt] = m1; ri2[nt] = c1;
            }
        }
    }

    // merge 4 sources per token (2 waves x 2 lane-halves)
    __syncthreads();
    unsigned* mk1 = (unsigned*)smem;
    int*      mi1 = (int*)(smem + 1024);
    unsigned* mk2 = (unsigned*)(smem + 2048);
    int*      mi2 = (int*)(smem + 3072);
    #pragma unroll
    for (int nt = 0; nt < 2; ++nt) {
        int T = nt * 32 + col;
        int src = wv * 2 + h;
        mk1[T * 4 + src] = rv1[nt]; mi1[T * 4 + src] = ri1[nt];
        mk2[T * 4 + src] = rv2[nt]; mi2[T * 4 + src] = ri2[nt];
    }
    __syncthreads();
    if (t < 64) {
        unsigned b1k = 0u, b2k = 0u; int b1i = 0x7FFFFFFF, b2i = 0x7FFFFFFF;
        #pragma unroll
        for (int src = 0; src < 4; ++src) {
            unsigned k = mk1[t * 4 + src]; int i = mi1[t * 4 + src];
            if (k > b1k || (k == b1k && i < b1i)) { b2k = b1k; b2i = b1i; b1k = k; b1i = i; }
            else if (k > b2k || (k == b2k && i < b2i)) { b2k = k; b2i = i; }
            k = mk2[t * 4 + src]; i = mi2[t * 4 + src];
            if (k > b1k || (k == b1k && i < b1i)) { b2k = b1k; b2i = b1i; b1k = k; b1i = i; }
            else if (k > b2k || (k == b2k && i < b2i)) { b2k = k; b2i = i; }
        }
        int n = tokBase + t;
        cand[((size_t)part * N_TOK + n) * 2 + 0] = b1i;
        cand[((size_t)part * N_TOK + n) * 2 + 1] = b2i;
    }
}

// ---------------------------------------------------------------------------
// Kernel 3 (fused rescore + gather): block per (b,h) = 32 tokens.
// 16 candidates/token (8 partitions x 2), 4 lanes per candidate, one pass.
// Exact fp32 score s2[k]-2*dot, jnp.argmin tie semantics. Then gather+
// transpose-write.
// ---------------------------------------------------------------------------
__global__ __launch_bounds__(256) void rescore_gather(
        const float* __restrict__ ztn, const float* __restrict__ e_n,
        const float* __restrict__ s2, const int* __restrict__ cand,
        float* __restrict__ out, float* __restrict__ idxf) {
    __shared__ __align__(16) char sm[32 * 257 * 4];
    __shared__ int idxs[32];
    float* zrow = (float*)sm;        // [32][256] phase B
    float* tile = (float*)sm;        // [32][257] phase C
    int t = threadIdx.x;
    int bid = blockIdx.x;            // b*32 + h
    int b = bid >> 5, h = bid & 31;
    int n_base = bid * 32;
    int wv = t >> 6, l = t & 63;

    // Phase A: stage token rows
    {
        const float* src = ztn + (size_t)n_base * C_DIM;
        #pragma unroll
        for (int j = 0; j < 8; ++j) {
            int fi = j * 1024 + t * 4;
            float4 v = *(const float4*)(src + fi);
            *(float4*)(zrow + fi) = v;
        }
    }
    __syncthreads();

    // Phase B: wave wv -> tokens wv*8+i; lane: candidate cs = l>>2, quarter p
    int cs = l >> 2, p = l & 3;
    int prt = cs >> 1, slot = cs & 1;
    for (int i = 0; i < 8; ++i) {
        int nl = wv * 8 + i;
        int n = n_base + nl;
        int c = cand[((size_t)prt * N_TOK + n) * 2 + slot];
        const float* er = e_n + (size_t)c * C_DIM + p * 64;
        const float* zr = zrow + nl * 256 + p * 64;
        float s = 0.f;
        #pragma unroll
        for (int j = 0; j < 16; ++j) {
            float4 e4 = *(const float4*)(er + j * 4);
            float4 z4 = *(const float4*)(zr + j * 4);
            s = fmaf(e4.x, z4.x, s); s = fmaf(e4.y, z4.y, s);
            s = fmaf(e4.z, z4.z, s); s = fmaf(e4.w, z4.w, s);
        }
        s += __shfl_xor(s, 1); s += __shfl_xor(s, 2);
        float bs = s2[c] - 2.f * s;
        int bi = c;
        #pragma unroll
        for (int d = 4; d < 64; d <<= 1) {
            float os = __shfl_xor(bs, d);
            int   oi = __shfl_xor(bi, d);
            if (os < bs || (os == bs && oi < bi)) { bs = os; bi = oi; }
        }
        if (l == 0) { idxs[nl] = bi; idxf[n] = (float)bi; }
    }
    __syncthreads();

    // Phase C: gather winning rows, transpose-write
    for (int r = 0; r < 32; ++r) {
        int k = idxs[r];
        tile[r * 257 + t] = e_n[(size_t)k * C_DIM + t];
    }
    __syncthreads();
    int w = t & 31, c0 = t >> 5;
    float* ob = out + ((size_t)(b * C_DIM) * H_ + h) * W_;
    #pragma unroll
    for (int it = 0; it < 32; ++it) {
        int c = it * 8 + c0;
        ob[(size_t)c * HW + w] = tile[w * 257 + c];
    }
}

// ---------------------------------------------------------------------------
extern "C" void kernel_launch(void* const* d_in, const int* in_sizes, int n_in,
                              void* d_out, int out_size, void* d_ws, size_t ws_size,
                              hipStream_t stream) {
    const float* z   = (const float*)d_in[0];
    const float* emb = (const float*)d_in[1];
    float* out  = (float*)d_out;
    float* idxf = out + (size_t)B_ * C_DIM * H_ * W_;

    char* ws = (char*)d_ws;
    size_t o = 0;
    float*  e_n  = (float*)(ws + o);  o += (size_t)K_CODES * C_DIM * 4;   // 8 MB
    float*  s2   = (float*)(ws + o);  o += 32768;
    float*  ztn  = (float*)(ws + o);  o += (size_t)N_TOK * C_DIM * 4;     // 16 MB
    ushort* Chi  = (ushort*)(ws + o); o += (size_t)K_CODES * C_DIM * 2;   // 4 MB
    ushort* Clo  = (ushort*)(ws + o); o += (size_t)K_CODES * C_DIM * 2;   // 4 MB
    ushort* Thi  = (ushort*)(ws + o); o += (size_t)N_TOK * C_DIM * 2;     // 8 MB
    ushort* Tlo  = (ushort*)(ws + o); o += (size_t)N_TOK * C_DIM * 2;     // 8 MB
    int*    cand = (int*)(ws + o);    o += (size_t)KSPLIT * N_TOK * 2 * 4; // 1 MB

    hipLaunchKernelGGL(norm_pack, dim3(256 + 512), dim3(256), 0, stream,
                       emb, z, e_n, s2, Chi, Clo, ztn, Thi, Tlo);
    hipLaunchKernelGGL(score_topk, dim3(N_TOK / 64, KSPLIT), dim3(128), 0, stream,
                       Chi, Clo, Thi, Tlo, cand);
    hipLaunchKernelGGL(rescore_gather, dim3(B_ * H_), dim3(256), 0, stream,
                       ztn, e_n, s2, cand, out, idxf);
}

// Round 6
// 347.406 us; speedup vs baseline: 1.6414x; 1.6414x over previous
//
#include <hip/hip_runtime.h>
#include <math.h>
#include <float.h>

#define K_CODES 8192
#define C_DIM   256
#define N_TOK   16384
#define B_      16
#define H_      32
#define W_      32
#define HW      1024
#define KSPLIT  8
#define TOKS_PER_BLK   128
#define CODES_PER_ITER 128

typedef short  short8  __attribute__((ext_vector_type(8)));
typedef float  floatx4 __attribute__((ext_vector_type(4)));

__device__ inline ushort f32_to_bf16_rne(float x) {
    union { float f; unsigned u; } v; v.f = x;
    unsigned u = v.u;
    return (ushort)((u + 0x7FFFu + ((u >> 16) & 1u)) >> 16);
}
__device__ inline float bf16_bits_to_f32(ushort h) {
    union { unsigned u; float f; } v; v.u = ((unsigned)h) << 16;
    return v.f;
}
__device__ inline unsigned umax_(unsigned a, unsigned b) { return a > b ? a : b; }
__device__ inline unsigned umin_(unsigned a, unsigned b) { return a < b ? a : b; }

// async 16B global->LDS: g per-lane (base + lane*16), l wave-uniform.
__device__ inline void g2l16(const void* g, void* l) {
    __builtin_amdgcn_global_load_lds((const __attribute__((address_space(1))) unsigned int*)g,
                                     (__attribute__((address_space(3))) unsigned int*)l,
                                     16, 0, 0);
}

// Swizzled bf16 layout (rows x 256 ch), 16-row groups (RG = row>>4):
//   byte addr = RG*8192 + cb*512 + h*256 + ri*16  (cb=ch>>4, h=(ch>>3)&1, ri=row&15)
// Frag group (16 rows x 32 ch) = contiguous 1KB at RG*8192 + s*1024, lane-linear.

// ---------------------------------------------------------------------------
// Kernel 1 (fused): bid<256 -> codebook (32 codes): e_n fp32, s2, swizzled
// Chi/Clo. bid>=256 -> tokens ((b,h), 32 tokens): ztn fp32, swizzled Thi/Tlo.
// ---------------------------------------------------------------------------
__global__ __launch_bounds__(256) void norm_pack(
        const float* __restrict__ emb, const float* __restrict__ z,
        float* __restrict__ e_n, float* __restrict__ s2,
        ushort* __restrict__ Chi, ushort* __restrict__ Clo,
        float* __restrict__ ztn, ushort* __restrict__ Thi, ushort* __restrict__ Tlo) {
    __shared__ float tile[32][257];
    __shared__ float pvt[32][9];
    __shared__ float pvt2[32][9];
    __shared__ float inv[32];
    int t = threadIdx.x;
    int bid = blockIdx.x;
    if (bid < 256) {
        // ---- codebook path ----
        int k0 = bid * 32;
        int r = t >> 3, cp = t & 7;
        const float* src = emb + (size_t)(k0 + r) * C_DIM + cp * 32;
        float ss = 0.f;
        #pragma unroll
        for (int j = 0; j < 8; ++j) {
            float4 v = *(const float4*)(src + j * 4);
            tile[r][cp * 32 + j * 4 + 0] = v.x;
            tile[r][cp * 32 + j * 4 + 1] = v.y;
            tile[r][cp * 32 + j * 4 + 2] = v.z;
            tile[r][cp * 32 + j * 4 + 3] = v.w;
            ss = fmaf(v.x, v.x, ss); ss = fmaf(v.y, v.y, ss);
            ss = fmaf(v.z, v.z, ss); ss = fmaf(v.w, v.w, ss);
        }
        pvt[r][cp] = ss;
        __syncthreads();
        if (t < 32) {
            float a = 0.f;
            #pragma unroll
            for (int p = 0; p < 8; ++p) a += pvt[t][p];
            inv[t] = 1.0f / fmaxf(sqrtf(a), 1e-12f);
        }
        __syncthreads();
        float iv = inv[r];
        float s2p = 0.f;
        float* dst = e_n + (size_t)(k0 + r) * C_DIM + cp * 32;
        #pragma unroll
        for (int j = 0; j < 8; ++j) {
            float a = tile[r][cp * 32 + j * 4 + 0] * iv;
            float b = tile[r][cp * 32 + j * 4 + 1] * iv;
            float c = tile[r][cp * 32 + j * 4 + 2] * iv;
            float d = tile[r][cp * 32 + j * 4 + 3] * iv;
            s2p = fmaf(a, a, s2p); s2p = fmaf(b, b, s2p);
            s2p = fmaf(c, c, s2p); s2p = fmaf(d, d, s2p);
            float4 o = {a, b, c, d};
            *(float4*)(dst + j * 4) = o;
        }
        pvt2[r][cp] = s2p;
        __syncthreads();
        if (t < 32) {
            float a = 0.f;
            #pragma unroll
            for (int p = 0; p < 8; ++p) a += pvt2[t][p];
            s2[k0 + t] = a;
        }
        int baseRG = bid * 2;
        char* chiB = (char*)Chi;
        char* cloB = (char*)Clo;
        #pragma unroll
        for (int e = 0; e < 4; ++e) {
            int p = e * 256 + t;
            int row = ((p >> 9) << 4) | (p & 15);
            int ch0 = (((p >> 5) & 15) << 4) | (((p >> 4) & 1) << 3);
            float rv = inv[row];
            union { ushort u[8]; uint4 v; } hs, ls;
            #pragma unroll
            for (int i = 0; i < 8; ++i) {
                float vv = tile[row][ch0 + i] * rv;
                ushort hb = f32_to_bf16_rne(vv);
                hs.u[i] = hb;
                ls.u[i] = f32_to_bf16_rne(vv - bf16_bits_to_f32(hb));
            }
            size_t addr = (size_t)(baseRG + (p >> 9)) * 8192 + (size_t)(p & 511) * 16;
            *(uint4*)(chiB + addr) = hs.v;
            *(uint4*)(cloB + addr) = ls.v;
        }
    } else {
        // ---- token path ----
        int tb = bid - 256;            // b*32 + h
        int b = tb >> 5, h = tb & 31;
        int w = t & 31, c0 = t >> 5;
        const float* zb = z + ((size_t)(b * C_DIM) * H_ + h) * W_;
        #pragma unroll
        for (int it = 0; it < 32; ++it) {
            int c = it * 8 + c0;
            tile[w][c] = zb[(size_t)c * HW + w];
        }
        __syncthreads();
        int part = t >> 5, w2 = t & 31;
        float s = 0.f;
        #pragma unroll
        for (int i = 0; i < 32; ++i) {
            float v = tile[w2][part * 32 + i];
            s = fmaf(v, v, s);
        }
        pvt[w2][part] = s;
        __syncthreads();
        if (t < 32) {
            float ss = 0.f;
            #pragma unroll
            for (int p = 0; p < 8; ++p) ss += pvt[t][p];
            inv[t] = 1.0f / fmaxf(sqrtf(ss), 1e-12f);
        }
        __syncthreads();
        int n_base = tb * 32;
        for (int r = 0; r < 32; ++r) {
            float val = tile[r][t] * inv[r];
            ztn[(size_t)(n_base + r) * C_DIM + t] = val;
        }
        int baseRG = tb * 2;
        char* thiB = (char*)Thi;
        char* tloB = (char*)Tlo;
        #pragma unroll
        for (int e = 0; e < 4; ++e) {
            int p = e * 256 + t;
            int row = ((p >> 9) << 4) | (p & 15);
            int ch0 = (((p >> 5) & 15) << 4) | (((p >> 4) & 1) << 3);
            float rv = inv[row];
            union { ushort u[8]; uint4 v; } hs, ls;
            #pragma unroll
            for (int i = 0; i < 8; ++i) {
                float vv = tile[row][ch0 + i] * rv;
                ushort hb = f32_to_bf16_rne(vv);
                hs.u[i] = hb;
                ls.u[i] = f32_to_bf16_rne(vv - bf16_bits_to_f32(hb));
            }
            size_t addr = (size_t)(baseRG + (p >> 9)) * 8192 + (size_t)(p & 511) * 16;
            *(uint4*)(thiB + addr) = hs.v;
            *(uint4*)(tloB + addr) = ls.v;
        }
    }
}

// ---------------------------------------------------------------------------
// Kernel 2: MFMA scan (round-3 wave structure). Block = 128 thr (2 waves),
// tile 128 tok x 128 codes; wave = 64 tok x 128 codes (ct=8, nt=4, acc
// 128 VGPR). All operands via global_load_lds into 32KB LDS. Grid (128, 8)
// = 1024 blocks = 4 resident/CU. Emits (key1,idx1,key2,idx2) per tok/part.
// ---------------------------------------------------------------------------
__global__ __launch_bounds__(128, 4) void score_topk(
        const ushort* __restrict__ Chi, const ushort* __restrict__ Clo,
        const ushort* __restrict__ Thi, const ushort* __restrict__ Tlo,
        uint4* __restrict__ cand) {
    // LDS: codes hi 8KB @0, lo 8KB @8192; tokens hi 8KB @16384, lo 8KB @24576
    __shared__ __align__(16) char smem[32768];
    int t = threadIdx.x;
    int l = t & 63, wv = t >> 6;
    int q = l >> 4, li = l & 15;
    int tokBase = blockIdx.x * TOKS_PER_BLK;
    int tokRG = tokBase >> 4;                 // 8 token RGs per block
    int part = blockIdx.y;
    int partBase = part * (K_CODES / KSPLIT); // 1024 codes per partition

    unsigned rv1[4], rv2[4]; int ri1[4], ri2[4];
    #pragma unroll
    for (int i = 0; i < 4; ++i) { rv1[i] = 0u; rv2[i] = 0u; ri1[i] = 0; ri2[i] = 0; }

    const char* chiB = (const char*)Chi;
    const char* cloB = (const char*)Clo;
    const char* thiB = (const char*)Thi;
    const char* tloB = (const char*)Tlo;

    for (int kt = 0; kt < (K_CODES / KSPLIT) / CODES_PER_ITER; ++kt) {  // 8
        int kbase = partBase + kt * CODES_PER_ITER;
        int codeRG = kbase >> 4;              // 8 code RGs per iter
        floatx4 acc[8][4];
        #pragma unroll
        for (int ct = 0; ct < 8; ++ct)
            #pragma unroll
            for (int nt = 0; nt < 4; ++nt) {
                floatx4 zz = {0.f, 0.f, 0.f, 0.f};
                acc[ct][nt] = zz;
            }

        for (int s = 0; s < 8; ++s) {
            __syncthreads();   // prior stage's readers done
            // 32 slices of 1KB; wave wv stages 16
            #pragma unroll
            for (int gi = 0; gi < 16; ++gi) {
                int grp = wv * 16 + gi;
                const char* gbase;
                int ldsOff;
                if (grp < 16) {
                    int hilo = grp & 1, ct = grp >> 1;
                    gbase = (hilo ? cloB : chiB) + (size_t)(codeRG + ct) * 8192;
                    ldsOff = ((hilo << 3) + ct) << 10;
                } else {
                    int gb = grp - 16;
                    int hilo = gb & 1, g = gb >> 1;
                    gbase = (hilo ? tloB : thiB) + (size_t)(tokRG + g) * 8192;
                    ldsOff = 16384 + (((hilo << 3) + g) << 10);
                }
                g2l16(gbase + s * 1024 + (l << 4), smem + ldsOff);
            }
            __syncthreads();   // DMA drained

            short8 bh[4], bl[4];
            #pragma unroll
            for (int nt = 0; nt < 4; ++nt) {
                int g = wv * 4 + nt;
                bh[nt] = *(const short8*)(smem + 16384 + (g << 10) + (l << 4));
                bl[nt] = *(const short8*)(smem + 16384 + ((8 + g) << 10) + (l << 4));
            }
            #pragma unroll
            for (int ct = 0; ct < 8; ++ct) {
                short8 ah = *(const short8*)(smem + (ct << 10) + (l << 4));
                short8 al = *(const short8*)(smem + ((8 + ct) << 10) + (l << 4));
                #pragma unroll
                for (int nt = 0; nt < 4; ++nt) {
                    acc[ct][nt] = __builtin_amdgcn_mfma_f32_16x16x32_bf16(al, bh[nt], acc[ct][nt], 0, 0, 0);
                    acc[ct][nt] = __builtin_amdgcn_mfma_f32_16x16x32_bf16(ah, bl[nt], acc[ct][nt], 0, 0, 0);
                    acc[ct][nt] = __builtin_amdgcn_mfma_f32_16x16x32_bf16(ah, bh[nt], acc[ct][nt], 0, 0, 0);
                }
            }
        }

        // packed-key top-2. key = (bits(d*0.25+1.25) & ~31) | (ct<<2|reg)
        #pragma unroll
        for (int nt = 0; nt < 4; ++nt) {
            unsigned m1 = 0u, m2 = 0u;
            #pragma unroll
            for (int ct = 0; ct < 8; ++ct) {
                unsigned k0 = (__float_as_uint(fmaf(acc[ct][nt][0], 0.25f, 1.25f)) & 0xFFFFFFE0u) | (unsigned)((ct << 2) | 0);
                unsigned k1 = (__float_as_uint(fmaf(acc[ct][nt][1], 0.25f, 1.25f)) & 0xFFFFFFE0u) | (unsigned)((ct << 2) | 1);
                unsigned k2 = (__float_as_uint(fmaf(acc[ct][nt][2], 0.25f, 1.25f)) & 0xFFFFFFE0u) | (unsigned)((ct << 2) | 2);
                unsigned k3 = (__float_as_uint(fmaf(acc[ct][nt][3], 0.25f, 1.25f)) & 0xFFFFFFE0u) | (unsigned)((ct << 2) | 3);
                unsigned tm = umax_(umax_(k0, k1), umax_(k2, k3));
                m2 = umax_(m2, umin_(tm, m1));
                m1 = umax_(m1, tm);
            }
            int off1 = (int)(m1 & 31u), off2 = (int)(m2 & 31u);
            int c1 = kbase + ((off1 >> 2) << 4) + (q << 2) + (off1 & 3);
            int c2 = kbase + ((off2 >> 2) << 4) + (q << 2) + (off2 & 3);
            if (m1 > rv1[nt]) {
                if (m2 > rv1[nt]) { rv2[nt] = m2; ri2[nt] = c2; }
                else              { rv2[nt] = rv1[nt]; ri2[nt] = ri1[nt]; }
                rv1[nt] = m1; ri1[nt] = c1;
            } else if (m1 > rv2[nt]) {
                rv2[nt] = m1; ri2[nt] = c1;
            }
        }
    }

    // merge across the 4 lane-quads per token (token = wv*64 + nt*16 + li)
    __syncthreads();
    unsigned* mk1 = (unsigned*)smem;
    int*      mi1 = (int*)(smem + 2048);
    unsigned* mk2 = (unsigned*)(smem + 4096);
    int*      mi2 = (int*)(smem + 6144);
    #pragma unroll
    for (int nt = 0; nt < 4; ++nt) {
        int T = wv * 64 + nt * 16 + li;
        mk1[T * 4 + q] = rv1[nt]; mi1[T * 4 + q] = ri1[nt];
        mk2[T * 4 + q] = rv2[nt]; mi2[T * 4 + q] = ri2[nt];
    }
    __syncthreads();
    {
        unsigned b1k = 0u, b2k = 0u; int b1i = 0x7FFFFFFF, b2i = 0x7FFFFFFF;
        #pragma unroll
        for (int qq = 0; qq < 4; ++qq) {
            unsigned k = mk1[t * 4 + qq]; int i = mi1[t * 4 + qq];
            if (k > b1k || (k == b1k && i < b1i)) { b2k = b1k; b2i = b1i; b1k = k; b1i = i; }
            else if (k > b2k || (k == b2k && i < b2i)) { b2k = k; b2i = i; }
            k = mk2[t * 4 + qq]; i = mi2[t * 4 + qq];
            if (k > b1k || (k == b1k && i < b1i)) { b2k = b1k; b2i = b1i; b1k = k; b1i = i; }
            else if (k > b2k || (k == b2k && i < b2i)) { b2k = k; b2i = i; }
        }
        uint4 o = {b1k, (unsigned)b1i, b2k, (unsigned)b2i};
        cand[(size_t)part * N_TOK + tokBase + t] = o;
    }
}

// ---------------------------------------------------------------------------
// Kernel 3: margin-gated rescore + gather. Block per (b,h) = 32 tokens.
// Merge 16 (key,idx) pairs; if key1-key2 > 1024 ULP the scan already decided
// (scan error ~100 ULP incl. quantization) -> no e_n reads. Else exact fp32
// rescore of 16 candidates (jnp.argmin tie semantics). Then gather+transpose.
// ---------------------------------------------------------------------------
__global__ __launch_bounds__(256) void rescore_gather(
        const float* __restrict__ ztn, const float* __restrict__ e_n,
        const float* __restrict__ s2, const uint4* __restrict__ cand,
        float* __restrict__ out, float* __restrict__ idxf) {
    __shared__ __align__(16) char sm[32 * 257 * 4];
    __shared__ uint4 cd[32][8];
    __shared__ int idxs[32];
    __shared__ int slowlist[32];
    __shared__ int nslow;
    float* zrow = (float*)sm;        // [32][256] (slow path)
    float* tile = (float*)sm;        // [32][257] (phase C)
    int t = threadIdx.x;
    int bid = blockIdx.x;            // b*32 + h
    int b = bid >> 5, h = bid & 31;
    int n_base = bid * 32;
    int wv = t >> 6, l = t & 63;

    if (t == 0) nslow = 0;
    // load candidates: thread t -> token t>>3, partition t&7
    cd[t >> 3][t & 7] = cand[(size_t)(t & 7) * N_TOK + n_base + (t >> 3)];
    // stage token rows (contiguous)
    {
        const float* src = ztn + (size_t)n_base * C_DIM;
        #pragma unroll
        for (int j = 0; j < 8; ++j) {
            int fi = j * 1024 + t * 4;
            float4 v = *(const float4*)(src + fi);
            *(float4*)(zrow + fi) = v;
        }
    }
    __syncthreads();

    if (t < 32) {
        unsigned b1k = 0u, b2k = 0u; int b1i = 0x7FFFFFFF, b2i = 0x7FFFFFFF;
        #pragma unroll
        for (int p = 0; p < 8; ++p) {
            uint4 c4 = cd[t][p];
            unsigned k = c4.x; int i = (int)c4.y;
            if (k > b1k || (k == b1k && i < b1i)) { b2k = b1k; b2i = b1i; b1k = k; b1i = i; }
            else if (k > b2k || (k == b2k && i < b2i)) { b2k = k; b2i = i; }
            k = c4.z; i = (int)c4.w;
            if (k > b1k || (k == b1k && i < b1i)) { b2k = b1k; b2i = b1i; b1k = k; b1i = i; }
            else if (k > b2k || (k == b2k && i < b2i)) { b2k = k; b2i = i; }
        }
        if (b1k - b2k > 1024u) {        // scan-decided (b1k >= b2k always)
            idxs[t] = b1i;
            idxf[n_base + t] = (float)b1i;
        } else {
            int s = atomicAdd(&nslow, 1);
            slowlist[s] = t;
        }
    }
    __syncthreads();
    int ns = nslow;
    // slow path: 16 candidates x 4 lanes each
    int cs = l >> 2, p4 = l & 3;
    int prt = cs >> 1, slot = cs & 1;
    for (int j = wv; j < ns; j += 4) {
        int tok = slowlist[j];
        int n = n_base + tok;
        uint4 c4 = cd[tok][prt];
        int c = (int)(slot ? c4.w : c4.y);
        const float* er = e_n + (size_t)c * C_DIM + p4 * 64;
        const float* zr = zrow + tok * 256 + p4 * 64;
        float s = 0.f;
        #pragma unroll
        for (int jj = 0; jj < 16; ++jj) {
            float4 e4 = *(const float4*)(er + jj * 4);
            float4 z4 = *(const float4*)(zr + jj * 4);
            s = fmaf(e4.x, z4.x, s); s = fmaf(e4.y, z4.y, s);
            s = fmaf(e4.z, z4.z, s); s = fmaf(e4.w, z4.w, s);
        }
        s += __shfl_xor(s, 1); s += __shfl_xor(s, 2);
        float bs = s2[c] - 2.f * s;
        int bi = c;
        #pragma unroll
        for (int d = 4; d < 64; d <<= 1) {
            float os = __shfl_xor(bs, d);
            int   oi = __shfl_xor(bi, d);
            if (os < bs || (os == bs && oi < bi)) { bs = os; bi = oi; }
        }
        if (l == 0) { idxs[tok] = bi; idxf[n] = (float)bi; }
    }
    __syncthreads();

    // Phase C: gather winning rows, transpose-write
    for (int r = 0; r < 32; ++r) {
        int k = idxs[r];
        tile[r * 257 + t] = e_n[(size_t)k * C_DIM + t];
    }
    __syncthreads();
    int w = t & 31, c0 = t >> 5;
    float* ob = out + ((size_t)(b * C_DIM) * H_ + h) * W_;
    #pragma unroll
    for (int it = 0; it < 32; ++it) {
        int c = it * 8 + c0;
        ob[(size_t)c * HW + w] = tile[w * 257 + c];
    }
}

// ---------------------------------------------------------------------------
extern "C" void kernel_launch(void* const* d_in, const int* in_sizes, int n_in,
                              void* d_out, int out_size, void* d_ws, size_t ws_size,
                              hipStream_t stream) {
    const float* z   = (const float*)d_in[0];
    const float* emb = (const float*)d_in[1];
    float* out  = (float*)d_out;
    float* idxf = out + (size_t)B_ * C_DIM * H_ * W_;

    char* ws = (char*)d_ws;
    size_t o = 0;
    float*  e_n  = (float*)(ws + o);  o += (size_t)K_CODES * C_DIM * 4;   // 8 MB
    float*  s2   = (float*)(ws + o);  o += 32768;
    float*  ztn  = (float*)(ws + o);  o += (size_t)N_TOK * C_DIM * 4;     // 16 MB
    ushort* Chi  = (ushort*)(ws + o); o += (size_t)K_CODES * C_DIM * 2;   // 4 MB
    ushort* Clo  = (ushort*)(ws + o); o += (size_t)K_CODES * C_DIM * 2;   // 4 MB
    ushort* Thi  = (ushort*)(ws + o); o += (size_t)N_TOK * C_DIM * 2;     // 8 MB
    ushort* Tlo  = (ushort*)(ws + o); o += (size_t)N_TOK * C_DIM * 2;     // 8 MB
    uint4*  cand = (uint4*)(ws + o);  o += (size_t)KSPLIT * N_TOK * 16;   // 2 MB

    hipLaunchKernelGGL(norm_pack, dim3(256 + B_ * H_), dim3(256), 0, stream,
                       emb, z, e_n, s2, Chi, Clo, ztn, Thi, Tlo);
    hipLaunchKernelGGL(score_topk, dim3(N_TOK / TOKS_PER_BLK, KSPLIT), dim3(128), 0, stream,
                       Chi, Clo, Thi, Tlo, cand);
    hipLaunchKernelGGL(rescore_gather, dim3(B_ * H_), dim3(256), 0, stream,
                       ztn, e_n, s2, cand, out, idxf);
}

// Round 7
// 248.889 us; speedup vs baseline: 2.2912x; 1.3958x over previous
//
#include <hip/hip_runtime.h>
#include <math.h>
#include <float.h>

#define K_CODES 8192
#define C_DIM   256
#define N_TOK   16384
#define B_      16
#define H_      32
#define W_      32
#define HW      1024
#define KSPLIT  16
#define TOKS_PER_BLK   256
#define CODES_PER_ITER 128

typedef short  short8  __attribute__((ext_vector_type(8)));
typedef float  floatx4 __attribute__((ext_vector_type(4)));

__device__ inline ushort f32_to_bf16_rne(float x) {
    union { float f; unsigned u; } v; v.f = x;
    unsigned u = v.u;
    return (ushort)((u + 0x7FFFu + ((u >> 16) & 1u)) >> 16);
}
__device__ inline float bf16_bits_to_f32(ushort h) {
    union { unsigned u; float f; } v; v.u = ((unsigned)h) << 16;
    return v.f;
}
__device__ inline unsigned umax_(unsigned a, unsigned b) { return a > b ? a : b; }
__device__ inline unsigned umin_(unsigned a, unsigned b) { return a < b ? a : b; }

// async 16B global->LDS: g per-lane (base + lane*16), l wave-uniform.
__device__ inline void g2l16(const void* g, void* l) {
    __builtin_amdgcn_global_load_lds((const __attribute__((address_space(1))) unsigned int*)g,
                                     (__attribute__((address_space(3))) unsigned int*)l,
                                     16, 0, 0);
}

// Swizzled bf16 layout (rows x 256 ch), 16-row groups (RG = row>>4):
//   byte addr = RG*8192 + cb*512 + h*256 + ri*16  (cb=ch>>4, h=(ch>>3)&1, ri=row&15)
// Frag group (16 rows x 32 ch) = contiguous 1KB at RG*8192 + s*1024, lane-linear.

// ---------------------------------------------------------------------------
// Kernel 1 (fused): bid<256 -> codebook (32 codes): e_n fp32, s2, swizzled
// Chi/Clo. bid>=256 -> tokens ((b,h), 32 tokens): ztn fp32, swizzled Thi/Tlo.
// ---------------------------------------------------------------------------
__global__ __launch_bounds__(256) void norm_pack(
        const float* __restrict__ emb, const float* __restrict__ z,
        float* __restrict__ e_n, float* __restrict__ s2,
        ushort* __restrict__ Chi, ushort* __restrict__ Clo,
        float* __restrict__ ztn, ushort* __restrict__ Thi, ushort* __restrict__ Tlo) {
    __shared__ float tile[32][257];
    __shared__ float pvt[32][9];
    __shared__ float pvt2[32][9];
    __shared__ float inv[32];
    int t = threadIdx.x;
    int bid = blockIdx.x;
    if (bid < 256) {
        // ---- codebook path ----
        int k0 = bid * 32;
        int r = t >> 3, cp = t & 7;
        const float* src = emb + (size_t)(k0 + r) * C_DIM + cp * 32;
        float ss = 0.f;
        #pragma unroll
        for (int j = 0; j < 8; ++j) {
            float4 v = *(const float4*)(src + j * 4);
            tile[r][cp * 32 + j * 4 + 0] = v.x;
            tile[r][cp * 32 + j * 4 + 1] = v.y;
            tile[r][cp * 32 + j * 4 + 2] = v.z;
            tile[r][cp * 32 + j * 4 + 3] = v.w;
            ss = fmaf(v.x, v.x, ss); ss = fmaf(v.y, v.y, ss);
            ss = fmaf(v.z, v.z, ss); ss = fmaf(v.w, v.w, ss);
        }
        pvt[r][cp] = ss;
        __syncthreads();
        if (t < 32) {
            float a = 0.f;
            #pragma unroll
            for (int p = 0; p < 8; ++p) a += pvt[t][p];
            inv[t] = 1.0f / fmaxf(sqrtf(a), 1e-12f);
        }
        __syncthreads();
        float iv = inv[r];
        float s2p = 0.f;
        float* dst = e_n + (size_t)(k0 + r) * C_DIM + cp * 32;
        #pragma unroll
        for (int j = 0; j < 8; ++j) {
            float a = tile[r][cp * 32 + j * 4 + 0] * iv;
            float b = tile[r][cp * 32 + j * 4 + 1] * iv;
            float c = tile[r][cp * 32 + j * 4 + 2] * iv;
            float d = tile[r][cp * 32 + j * 4 + 3] * iv;
            s2p = fmaf(a, a, s2p); s2p = fmaf(b, b, s2p);
            s2p = fmaf(c, c, s2p); s2p = fmaf(d, d, s2p);
            float4 o = {a, b, c, d};
            *(float4*)(dst + j * 4) = o;
        }
        pvt2[r][cp] = s2p;
        __syncthreads();
        if (t < 32) {
            float a = 0.f;
            #pragma unroll
            for (int p = 0; p < 8; ++p) a += pvt2[t][p];
            s2[k0 + t] = a;
        }
        int baseRG = bid * 2;
        char* chiB = (char*)Chi;
        char* cloB = (char*)Clo;
        #pragma unroll
        for (int e = 0; e < 4; ++e) {
            int p = e * 256 + t;
            int row = ((p >> 9) << 4) | (p & 15);
            int ch0 = (((p >> 5) & 15) << 4) | (((p >> 4) & 1) << 3);
            float rv = inv[row];
            union { ushort u[8]; uint4 v; } hs, ls;
            #pragma unroll
            for (int i = 0; i < 8; ++i) {
                float vv = tile[row][ch0 + i] * rv;
                ushort hb = f32_to_bf16_rne(vv);
                hs.u[i] = hb;
                ls.u[i] = f32_to_bf16_rne(vv - bf16_bits_to_f32(hb));
            }
            size_t addr = (size_t)(baseRG + (p >> 9)) * 8192 + (size_t)(p & 511) * 16;
            *(uint4*)(chiB + addr) = hs.v;
            *(uint4*)(cloB + addr) = ls.v;
        }
    } else {
        // ---- token path ----
        int tb = bid - 256;            // b*32 + h
        int b = tb >> 5, h = tb & 31;
        int w = t & 31, c0 = t >> 5;
        const float* zb = z + ((size_t)(b * C_DIM) * H_ + h) * W_;
        #pragma unroll
        for (int it = 0; it < 32; ++it) {
            int c = it * 8 + c0;
            tile[w][c] = zb[(size_t)c * HW + w];
        }
        __syncthreads();
        int part = t >> 5, w2 = t & 31;
        float s = 0.f;
        #pragma unroll
        for (int i = 0; i < 32; ++i) {
            float v = tile[w2][part * 32 + i];
            s = fmaf(v, v, s);
        }
        pvt[w2][part] = s;
        __syncthreads();
        if (t < 32) {
            float ss = 0.f;
            #pragma unroll
            for (int p = 0; p < 8; ++p) ss += pvt[t][p];
            inv[t] = 1.0f / fmaxf(sqrtf(ss), 1e-12f);
        }
        __syncthreads();
        int n_base = tb * 32;
        for (int r = 0; r < 32; ++r) {
            float val = tile[r][t] * inv[r];
            ztn[(size_t)(n_base + r) * C_DIM + t] = val;
        }
        int baseRG = tb * 2;
        char* thiB = (char*)Thi;
        char* tloB = (char*)Tlo;
        #pragma unroll
        for (int e = 0; e < 4; ++e) {
            int p = e * 256 + t;
            int row = ((p >> 9) << 4) | (p & 15);
            int ch0 = (((p >> 5) & 15) << 4) | (((p >> 4) & 1) << 3);
            float rv = inv[row];
            union { ushort u[8]; uint4 v; } hs, ls;
            #pragma unroll
            for (int i = 0; i < 8; ++i) {
                float vv = tile[row][ch0 + i] * rv;
                ushort hb = f32_to_bf16_rne(vv);
                hs.u[i] = hb;
                ls.u[i] = f32_to_bf16_rne(vv - bf16_bits_to_f32(hb));
            }
            size_t addr = (size_t)(baseRG + (p >> 9)) * 8192 + (size_t)(p & 511) * 16;
            *(uint4*)(thiB + addr) = hs.v;
            *(uint4*)(tloB + addr) = ls.v;
        }
    }
}

// ---------------------------------------------------------------------------
// Kernel 2: MFMA scan — EXACT round-3 (176 µs) compile shape: 256 thr /
// 4 waves, tile 256 tok x 128 codes, wave = 64 tok x 128 codes (ct=8, nt=4),
// 48KB LDS, 12 staging slices/wave, __launch_bounds__(256,2), VGPR=128.
// ONLY change: KSPLIT 8->16 => grid (64,16)=1024 blocks, 3 resident/CU via
// LDS cap, kt loop 4 iters. Emits (key1,idx1,key2,idx2) per tok/partition.
// ---------------------------------------------------------------------------
__global__ __launch_bounds__(256, 2) void score_topk(
        const ushort* __restrict__ Chi, const ushort* __restrict__ Clo,
        const ushort* __restrict__ Thi, const ushort* __restrict__ Tlo,
        uint4* __restrict__ cand) {
    // LDS: codes hi 8KB @0, lo 8KB @8192; tokens hi 16KB @16384, lo 16KB @32768
    __shared__ __align__(16) char smem[49152];
    int t = threadIdx.x;
    int l = t & 63, wv = t >> 6;
    int q = l >> 4, li = l & 15;
    int tokBase = blockIdx.x * TOKS_PER_BLK;
    int tokRG = tokBase >> 4;                 // 16 token RGs per block
    int part = blockIdx.y;
    int partBase = part * (K_CODES / KSPLIT); // 512 codes per partition

    unsigned rv1[4], rv2[4]; int ri1[4], ri2[4];
    #pragma unroll
    for (int i = 0; i < 4; ++i) { rv1[i] = 0u; rv2[i] = 0u; ri1[i] = 0; ri2[i] = 0; }

    const char* chiB = (const char*)Chi;
    const char* cloB = (const char*)Clo;
    const char* thiB = (const char*)Thi;
    const char* tloB = (const char*)Tlo;

    for (int kt = 0; kt < (K_CODES / KSPLIT) / CODES_PER_ITER; ++kt) {  // 4
        int kbase = partBase + kt * CODES_PER_ITER;
        int codeRG = kbase >> 4;              // 8 code RGs per iter
        floatx4 acc[8][4];
        #pragma unroll
        for (int ct = 0; ct < 8; ++ct)
            #pragma unroll
            for (int nt = 0; nt < 4; ++nt) {
                floatx4 zz = {0.f, 0.f, 0.f, 0.f};
                acc[ct][nt] = zz;
            }

        for (int s = 0; s < 8; ++s) {
            __syncthreads();   // prior stage's readers done
            // 48 slices of 1KB; wave wv stages 12
            #pragma unroll
            for (int gi = 0; gi < 12; ++gi) {
                int grp = wv * 12 + gi;
                const char* gbase;
                int ldsOff;
                if (grp < 16) {
                    int hilo = grp & 1, ct = grp >> 1;
                    gbase = (hilo ? cloB : chiB) + (size_t)(codeRG + ct) * 8192;
                    ldsOff = ((hilo << 3) + ct) << 10;
                } else {
                    int gb = grp - 16;
                    int hilo = gb & 1, g = gb >> 1;
                    gbase = (hilo ? tloB : thiB) + (size_t)(tokRG + g) * 8192;
                    ldsOff = 16384 + (((hilo << 4) + g) << 10);
                }
                g2l16(gbase + s * 1024 + (l << 4), smem + ldsOff);
            }
            __syncthreads();   // DMA drained

            short8 bh[4], bl[4];
            #pragma unroll
            for (int nt = 0; nt < 4; ++nt) {
                int g = wv * 4 + nt;
                bh[nt] = *(const short8*)(smem + 16384 + (g << 10) + (l << 4));
                bl[nt] = *(const short8*)(smem + 16384 + ((16 + g) << 10) + (l << 4));
            }
            #pragma unroll
            for (int ct = 0; ct < 8; ++ct) {
                short8 ah = *(const short8*)(smem + (ct << 10) + (l << 4));
                short8 al = *(const short8*)(smem + ((8 + ct) << 10) + (l << 4));
                #pragma unroll
                for (int nt = 0; nt < 4; ++nt) {
                    acc[ct][nt] = __builtin_amdgcn_mfma_f32_16x16x32_bf16(al, bh[nt], acc[ct][nt], 0, 0, 0);
                    acc[ct][nt] = __builtin_amdgcn_mfma_f32_16x16x32_bf16(ah, bl[nt], acc[ct][nt], 0, 0, 0);
                    acc[ct][nt] = __builtin_amdgcn_mfma_f32_16x16x32_bf16(ah, bh[nt], acc[ct][nt], 0, 0, 0);
                }
            }
        }

        // packed-key top-2. key = (bits(d*0.25+1.25) & ~31) | (ct<<2|reg)
        #pragma unroll
        for (int nt = 0; nt < 4; ++nt) {
            unsigned m1 = 0u, m2 = 0u;
            #pragma unroll
            for (int ct = 0; ct < 8; ++ct) {
                unsigned k0 = (__float_as_uint(fmaf(acc[ct][nt][0], 0.25f, 1.25f)) & 0xFFFFFFE0u) | (unsigned)((ct << 2) | 0);
                unsigned k1 = (__float_as_uint(fmaf(acc[ct][nt][1], 0.25f, 1.25f)) & 0xFFFFFFE0u) | (unsigned)((ct << 2) | 1);
                unsigned k2 = (__float_as_uint(fmaf(acc[ct][nt][2], 0.25f, 1.25f)) & 0xFFFFFFE0u) | (unsigned)((ct << 2) | 2);
                unsigned k3 = (__float_as_uint(fmaf(acc[ct][nt][3], 0.25f, 1.25f)) & 0xFFFFFFE0u) | (unsigned)((ct << 2) | 3);
                unsigned tm = umax_(umax_(k0, k1), umax_(k2, k3));
                m2 = umax_(m2, umin_(tm, m1));
                m1 = umax_(m1, tm);
            }
            int off1 = (int)(m1 & 31u), off2 = (int)(m2 & 31u);
            int c1 = kbase + ((off1 >> 2) << 4) + (q << 2) + (off1 & 3);
            int c2 = kbase + ((off2 >> 2) << 4) + (q << 2) + (off2 & 3);
            if (m1 > rv1[nt]) {
                if (m2 > rv1[nt]) { rv2[nt] = m2; ri2[nt] = c2; }
                else              { rv2[nt] = rv1[nt]; ri2[nt] = ri1[nt]; }
                rv1[nt] = m1; ri1[nt] = c1;
            } else if (m1 > rv2[nt]) {
                rv2[nt] = m1; ri2[nt] = c1;
            }
        }
    }

    // merge across the 4 lane-quads per token (token = wv*64 + nt*16 + li)
    __syncthreads();
    unsigned* mk1 = (unsigned*)smem;
    int*      mi1 = (int*)(smem + 4096);
    unsigned* mk2 = (unsigned*)(smem + 8192);
    int*      mi2 = (int*)(smem + 12288);
    #pragma unroll
    for (int nt = 0; nt < 4; ++nt) {
        int T = wv * 64 + nt * 16 + li;
        mk1[T * 4 + q] = rv1[nt]; mi1[T * 4 + q] = ri1[nt];
        mk2[T * 4 + q] = rv2[nt]; mi2[T * 4 + q] = ri2[nt];
    }
    __syncthreads();
    {
        unsigned b1k = 0u, b2k = 0u; int b1i = 0x7FFFFFFF, b2i = 0x7FFFFFFF;
        #pragma unroll
        for (int qq = 0; qq < 4; ++qq) {
            unsigned k = mk1[t * 4 + qq]; int i = mi1[t * 4 + qq];
            if (k > b1k || (k == b1k && i < b1i)) { b2k = b1k; b2i = b1i; b1k = k; b1i = i; }
            else if (k > b2k || (k == b2k && i < b2i)) { b2k = k; b2i = i; }
            k = mk2[t * 4 + qq]; i = mi2[t * 4 + qq];
            if (k > b1k || (k == b1k && i < b1i)) { b2k = b1k; b2i = b1i; b1k = k; b1i = i; }
            else if (k > b2k || (k == b2k && i < b2i)) { b2k = k; b2i = i; }
        }
        uint4 o = {b1k, (unsigned)b1i, b2k, (unsigned)b2i};
        cand[(size_t)part * N_TOK + tokBase + t] = o;
    }
}

// ---------------------------------------------------------------------------
// Kernel 3: margin-gated rescore + gather. Block per (b,h) = 32 tokens.
// Merge 32 (key,idx) pairs (16 partitions x 2); if key1-key2 > 1024 ULP the
// scan already decided (scan error ~100 ULP) -> no e_n reads. Else exact
// fp32 rescore of 32 candidates (jnp.argmin tie semantics). Then gather+
// transpose-write.
// ---------------------------------------------------------------------------
__global__ __launch_bounds__(256) void rescore_gather(
        const float* __restrict__ ztn, const float* __restrict__ e_n,
        const float* __restrict__ s2, const uint4* __restrict__ cand,
        float* __restrict__ out, float* __restrict__ idxf) {
    __shared__ __align__(16) char sm[32 * 257 * 4];
    __shared__ uint4 cd[32][16];
    __shared__ int idxs[32];
    __shared__ int slowlist[32];
    __shared__ int nslow;
    float* zrow = (float*)sm;        // [32][256] (slow path)
    float* tile = (float*)sm;        // [32][257] (phase C)
    int t = threadIdx.x;
    int bid = blockIdx.x;            // b*32 + h
    int b = bid >> 5, h = bid & 31;
    int n_base = bid * 32;
    int wv = t >> 6, l = t & 63;

    if (t == 0) nslow = 0;
    // load candidates: thread t -> token t>>3, partitions t&7 and 8+(t&7)
    {
        int tok = t >> 3, p = t & 7;
        cd[tok][p]     = cand[(size_t)p * N_TOK + n_base + tok];
        cd[tok][p + 8] = cand[(size_t)(p + 8) * N_TOK + n_base + tok];
    }
    // stage token rows (contiguous)
    {
        const float* src = ztn + (size_t)n_base * C_DIM;
        #pragma unroll
        for (int j = 0; j < 8; ++j) {
            int fi = j * 1024 + t * 4;
            float4 v = *(const float4*)(src + fi);
            *(float4*)(zrow + fi) = v;
        }
    }
    __syncthreads();

    if (t < 32) {
        unsigned b1k = 0u, b2k = 0u; int b1i = 0x7FFFFFFF, b2i = 0x7FFFFFFF;
        #pragma unroll
        for (int p = 0; p < 16; ++p) {
            uint4 c4 = cd[t][p];
            unsigned k = c4.x; int i = (int)c4.y;
            if (k > b1k || (k == b1k && i < b1i)) { b2k = b1k; b2i = b1i; b1k = k; b1i = i; }
            else if (k > b2k || (k == b2k && i < b2i)) { b2k = k; b2i = i; }
            k = c4.z; i = (int)c4.w;
            if (k > b1k || (k == b1k && i < b1i)) { b2k = b1k; b2i = b1i; b1k = k; b1i = i; }
            else if (k > b2k || (k == b2k && i < b2i)) { b2k = k; b2i = i; }
        }
        if (b1k - b2k > 1024u) {        // scan-decided (b1k >= b2k always)
            idxs[t] = b1i;
            idxf[n_base + t] = (float)b1i;
        } else {
            int s = atomicAdd(&nslow, 1);
            slowlist[s] = t;
        }
    }
    __syncthreads();
    int ns = nslow;
    // slow path: 32 candidates x 2 lanes each
    int cs = l >> 1, p2 = l & 1;
    int prt = cs >> 1, slot = cs & 1;
    for (int j = wv; j < ns; j += 4) {
        int tok = slowlist[j];
        int n = n_base + tok;
        uint4 c4 = cd[tok][prt];
        int c = (int)(slot ? c4.w : c4.y);
        const float* er = e_n + (size_t)c * C_DIM + p2 * 128;
        const float* zr = zrow + tok * 256 + p2 * 128;
        float s = 0.f;
        #pragma unroll
        for (int jj = 0; jj < 32; ++jj) {
            float4 e4 = *(const float4*)(er + jj * 4);
            float4 z4 = *(const float4*)(zr + jj * 4);
            s = fmaf(e4.x, z4.x, s); s = fmaf(e4.y, z4.y, s);
            s = fmaf(e4.z, z4.z, s); s = fmaf(e4.w, z4.w, s);
        }
        s += __shfl_xor(s, 1);
        float bs = s2[c] - 2.f * s;
        int bi = c;
        #pragma unroll
        for (int d = 2; d < 64; d <<= 1) {
            float os = __shfl_xor(bs, d);
            int   oi = __shfl_xor(bi, d);
            if (os < bs || (os == bs && oi < bi)) { bs = os; bi = oi; }
        }
        if (l == 0) { idxs[tok] = bi; idxf[n] = (float)bi; }
    }
    __syncthreads();

    // Phase C: gather winning rows, transpose-write
    for (int r = 0; r < 32; ++r) {
        int k = idxs[r];
        tile[r * 257 + t] = e_n[(size_t)k * C_DIM + t];
    }
    __syncthreads();
    int w = t & 31, c0 = t >> 5;
    float* ob = out + ((size_t)(b * C_DIM) * H_ + h) * W_;
    #pragma unroll
    for (int it = 0; it < 32; ++it) {
        int c = it * 8 + c0;
        ob[(size_t)c * HW + w] = tile[w * 257 + c];
    }
}

// ---------------------------------------------------------------------------
extern "C" void kernel_launch(void* const* d_in, const int* in_sizes, int n_in,
                              void* d_out, int out_size, void* d_ws, size_t ws_size,
                              hipStream_t stream) {
    const float* z   = (const float*)d_in[0];
    const float* emb = (const float*)d_in[1];
    float* out  = (float*)d_out;
    float* idxf = out + (size_t)B_ * C_DIM * H_ * W_;

    char* ws = (char*)d_ws;
    size_t o = 0;
    float*  e_n  = (float*)(ws + o);  o += (size_t)K_CODES * C_DIM * 4;   // 8 MB
    float*  s2   = (float*)(ws + o);  o += 32768;
    float*  ztn  = (float*)(ws + o);  o += (size_t)N_TOK * C_DIM * 4;     // 16 MB
    ushort* Chi  = (ushort*)(ws + o); o += (size_t)K_CODES * C_DIM * 2;   // 4 MB
    ushort* Clo  = (ushort*)(ws + o); o += (size_t)K_CODES * C_DIM * 2;   // 4 MB
    ushort* Thi  = (ushort*)(ws + o); o += (size_t)N_TOK * C_DIM * 2;     // 8 MB
    ushort* Tlo  = (ushort*)(ws + o); o += (size_t)N_TOK * C_DIM * 2;     // 8 MB
    uint4*  cand = (uint4*)(ws + o);  o += (size_t)KSPLIT * N_TOK * 16;   // 4 MB

    hipLaunchKernelGGL(norm_pack, dim3(256 + B_ * H_), dim3(256), 0, stream,
                       emb, z, e_n, s2, Chi, Clo, ztn, Thi, Tlo);
    hipLaunchKernelGGL(score_topk, dim3(N_TOK / TOKS_PER_BLK, KSPLIT), dim3(256), 0, stream,
                       Chi, Clo, Thi, Tlo, cand);
    hipLaunchKernelGGL(rescore_gather, dim3(B_ * H_), dim3(256), 0, stream,
                       ztn, e_n, s2, cand, out, idxf);
}